// Round 1
// baseline (329.327 us; speedup 1.0000x reference)
//
#include <hip/hip_runtime.h>
#include <math.h>

#define L_MAX 2048
#define BATCH 64
#define DIM   256
#define CCH   512
#define ROWSTRIDE (BATCH * DIM)   // floats between consecutive l at fixed b

// ws layout (floats):
#define HQ_OFF   0          // 64*256  = 16384
#define WF_OFF   16384      // 3*256   = 768
#define SUMS_OFF 17152      // 64*32 (one cache line per b) = 2048
#define HARD_OFF 19200      // 2048*64 = 131072
#define PART_OFF 150272     // 32*64*256 = 524288
#define SUMS_STRIDE 32

__device__ __forceinline__ float fast_tanh(float x) {
    float ax = fabsf(x);
    float e  = __expf(2.0f * ax);                       // inf for big ax -> r=1
    float r  = 1.0f - 2.0f * __builtin_amdgcn_rcpf(e + 1.0f);
    return copysignf(r, x);
}

// Kernel A: hq[b][d] = sum_k ht_query[b][k]*W_query[d][k]
//           wf[j][d] = sum_c W_conv[c][0][j]*W_att_past[d][c]
//           block 0 additionally zeroes sums[].
__global__ __launch_bounds__(256) void prep_kernel(
    const float* __restrict__ ht_query, const float* __restrict__ W_query,
    const float* __restrict__ W_conv,   const float* __restrict__ W_att_past,
    float* __restrict__ hq, float* __restrict__ wf, float* __restrict__ sums) {
    int t   = threadIdx.x;
    int blk = blockIdx.x;
    if (blk == 0 && t < BATCH) sums[t * SUMS_STRIDE] = 0.f;
    __shared__ float q[DIM];
    if (blk < BATCH) {
        q[t] = ht_query[blk * DIM + t];
        __syncthreads();
        const float4* wrow = (const float4*)(W_query + t * DIM);
        float acc = 0.f;
        #pragma unroll 8
        for (int k = 0; k < DIM / 4; k++) {
            float4 wv = wrow[k];
            acc += q[4*k] * wv.x + q[4*k+1] * wv.y + q[4*k+2] * wv.z + q[4*k+3] * wv.w;
        }
        hq[blk * DIM + t] = acc;
    } else {
        int j = blk - BATCH;
        const float4* wrow = (const float4*)(W_att_past + t * CCH);
        float acc = 0.f;
        #pragma unroll 8
        for (int c = 0; c < CCH / 4; c++) {
            float4 wv = wrow[c];
            acc += W_conv[(4*c  ) * 3 + j] * wv.x + W_conv[(4*c+1) * 3 + j] * wv.y
                 + W_conv[(4*c+2) * 3 + j] * wv.z + W_conv[(4*c+3) * 3 + j] * wv.w;
        }
        wf[j * DIM + t] = acc;
    }
}

// Fused kernel: score + hard + partial ct in one pass.
// block = (b, chunk of 64 l's); 4 waves x 16 rows.
//
// Latency-bound fix (this revision): the old version had TWO serialized
// memory round-trips per wave (key burst -> score -> h -> cndmask'ed val
// burst), and at VGPR=60 the compiler re-batched the "burst" into small
// vmcnt(0)-drained groups (~5 exposed latencies/wave, 17% HBM BW, 16% VALU).
// Now: issue mask + key + val loads ALL up front, unconditionally, and pin
// them above the compute with sched_barrier(0). Score compute waits only on
// keys (vmcnt(16), vals still in flight); val consumption finds data
// resident. acc += v*h with h==0 contributes exactly 0, so unconditional
// val reads are numerically identical to the old row-0 dummy-read trick.
// __launch_bounds__(256,2) permits the ~200-VGPR live set (2 waves/SIMD;
// 32 loads x 4KB in flight per wave is ample MLP for 900cy HBM latency).
__global__ __launch_bounds__(256, 2) void fused_kernel(
    const float* __restrict__ ctx_key, const float* __restrict__ ctx_val,
    const float* __restrict__ ctx_mask, const float* __restrict__ att_past,
    const float* __restrict__ hq, const float* __restrict__ wf,
    const float* __restrict__ b_att_past, const float* __restrict__ W_attn,
    const float* __restrict__ b_attn,
    float* __restrict__ hard_raw, float* __restrict__ sums,
    float* __restrict__ part) {
    int b     = blockIdx.x & 63;
    int chunk = blockIdx.x >> 6;
    int w     = threadIdx.x >> 6;
    int lane  = threadIdx.x & 63;
    int d0    = lane << 2;
    int l0    = chunk * 64 + w * 16;

    float4 hq4 = *(const float4*)(hq + b * DIM + d0);
    float4 bp  = *(const float4*)(b_att_past + d0);
    hq4.x += bp.x; hq4.y += bp.y; hq4.z += bp.z; hq4.w += bp.w;
    float4 w0  = *(const float4*)(wf + d0);
    float4 w1  = *(const float4*)(wf + DIM + d0);
    float4 w2  = *(const float4*)(wf + 2 * DIM + d0);
    float4 wa  = *(const float4*)(W_attn + d0);
    float battn = b_attn[0];
    const float* apb = att_past + b * L_MAX;

    // att_past window [l0-1, l0+16]: ap[i] = apb[l0-1+i]
    float ap[18];
    {
        float4 t0 = *(const float4*)(apb + l0);
        float4 t1 = *(const float4*)(apb + l0 + 4);
        float4 t2 = *(const float4*)(apb + l0 + 8);
        float4 t3 = *(const float4*)(apb + l0 + 12);
        ap[1]=t0.x; ap[2]=t0.y; ap[3]=t0.z; ap[4]=t0.w;
        ap[5]=t1.x; ap[6]=t1.y; ap[7]=t1.z; ap[8]=t1.w;
        ap[9]=t2.x; ap[10]=t2.y; ap[11]=t2.z; ap[12]=t2.w;
        ap[13]=t3.x; ap[14]=t3.y; ap[15]=t3.z; ap[16]=t3.w;
        ap[0]  = (l0 > 0)          ? apb[l0 - 1]  : 0.f;
        ap[17] = (l0 + 16 < L_MAX) ? apb[l0 + 16] : 0.f;
    }

    const float* key_base = ctx_key + (size_t)(l0 * BATCH + b) * DIM + d0;
    const float* val_base = ctx_val + (size_t)(l0 * BATCH + b) * DIM + d0;

    // ---- Phase 1: issue EVERYTHING: 16 mask scalars, 16 key rows, 16 val
    //      rows -- one burst, no dependent second phase. ----
    float  m16[16];
    float4 k16[16];
    float4 v16[16];
    #pragma unroll
    for (int j = 0; j < 16; j++)
        m16[j] = ctx_mask[(l0 + j) * BATCH + b];
    #pragma unroll
    for (int j = 0; j < 16; j++)
        k16[j] = *(const float4*)(key_base + (size_t)j * ROWSTRIDE);
    #pragma unroll
    for (int j = 0; j < 16; j++)
        v16[j] = *(const float4*)(val_base + (size_t)j * ROWSTRIDE);
    // Pin all loads above the compute: the scheduler may not sink them into
    // the consumers (which is what produced the VGPR=60 re-batched version).
    __builtin_amdgcn_sched_barrier(0);

    // ---- Phase 2: 16 scores + butterfly (waits only on keys; vals in flight) ----
    float p[16];
    #pragma unroll
    for (int j = 0; j < 16; j++) {
        float am = ap[j], a0 = ap[j + 1], a1 = ap[j + 2];
        float x0 = k16[j].x + hq4.x + am * w0.x + a0 * w1.x + a1 * w2.x;
        float x1 = k16[j].y + hq4.y + am * w0.y + a0 * w1.y + a1 * w2.y;
        float x2 = k16[j].z + hq4.z + am * w0.z + a0 * w1.z + a1 * w2.z;
        float x3 = k16[j].w + hq4.w + am * w0.w + a0 * w1.w + a1 * w2.w;
        p[j] = fast_tanh(x0) * wa.x + fast_tanh(x1) * wa.y +
               fast_tanh(x2) * wa.z + fast_tanh(x3) * wa.w;
    }
    #pragma unroll
    for (int off = 32; off > 0; off >>= 1) {
        #pragma unroll
        for (int j = 0; j < 16; j++)
            p[j] += __shfl_xor(p[j], off, 64);
    }

    float h[16];
    float cnt = 0.f;
    #pragma unroll
    for (int j = 0; j < 16; j++) {
        h[j] = (p[j] + battn >= 0.f) ? m16[j] : 0.f;
        cnt += h[j];
    }
    if (lane == 0) {
        #pragma unroll
        for (int j = 0; j < 16; j++)
            hard_raw[(l0 + j) * BATCH + b] = h[j];
    }

    // ---- Phase 3: vals already resident; pure FMA ----
    float4 acc = make_float4(0.f, 0.f, 0.f, 0.f);
    #pragma unroll
    for (int j = 0; j < 16; j++) {
        acc.x += v16[j].x * h[j]; acc.y += v16[j].y * h[j];
        acc.z += v16[j].z * h[j]; acc.w += v16[j].w * h[j];
    }

    __shared__ float red[4 * DIM];
    *(float4*)(red + w * DIM + d0) = acc;
    __shared__ float c4[4];
    if (lane == 0) c4[w] = cnt;
    __syncthreads();
    int d = threadIdx.x;
    float s = red[d] + red[DIM + d] + red[2 * DIM + d] + red[3 * DIM + d];
    part[(size_t)(chunk * BATCH + b) * DIM + d] = s;
    if (threadIdx.x == 0)
        atomicAdd(&sums[b * SUMS_STRIDE], c4[0] + c4[1] + c4[2] + c4[3]);
}

// Tail: blocks 0..63   -> ct[b][d] = (sum_chunk part) / (Z_b+1e-10)
//       blocks 64..191 -> out_hard[l][b] = hard_raw[l][b] / (Z_b+1e-10)
__global__ __launch_bounds__(256) void tail_kernel(
    const float* __restrict__ part, const float* __restrict__ hard_raw,
    const float* __restrict__ sums,
    float* __restrict__ ct, float* __restrict__ out_hard) {
    if (blockIdx.x < BATCH) {
        int b = blockIdx.x;
        int d = threadIdx.x;
        float s = 0.f;
        #pragma unroll 8
        for (int c = 0; c < 32; c++)
            s += part[(size_t)(c * BATCH + b) * DIM + d];
        float invZ = 1.0f / (sums[b * SUMS_STRIDE] + 1e-10f);
        ct[b * DIM + d] = s * invZ;
    } else {
        int i = (blockIdx.x - BATCH) * 256 + threadIdx.x;   // 4 elems each
        float4 h = *(const float4*)(hard_raw + (size_t)i * 4);
        int b0 = (i * 4) & 63;
        float4 o;
        o.x = h.x / (sums[(b0 + 0) * SUMS_STRIDE] + 1e-10f);
        o.y = h.y / (sums[(b0 + 1) * SUMS_STRIDE] + 1e-10f);
        o.z = h.z / (sums[(b0 + 2) * SUMS_STRIDE] + 1e-10f);
        o.w = h.w / (sums[(b0 + 3) * SUMS_STRIDE] + 1e-10f);
        *(float4*)(out_hard + (size_t)i * 4) = o;
    }
}

extern "C" void kernel_launch(void* const* d_in, const int* in_sizes, int n_in,
                              void* d_out, int out_size, void* d_ws, size_t ws_size,
                              hipStream_t stream) {
    const float* ctx_val    = (const float*)d_in[0];
    const float* ctx_key    = (const float*)d_in[1];
    const float* ctx_mask   = (const float*)d_in[2];
    const float* att_past   = (const float*)d_in[3];
    const float* ht_query   = (const float*)d_in[4];
    const float* W_conv     = (const float*)d_in[5];
    const float* W_query    = (const float*)d_in[6];
    const float* W_att_past = (const float*)d_in[7];
    const float* b_att_past = (const float*)d_in[8];
    const float* W_attn     = (const float*)d_in[9];
    const float* b_attn     = (const float*)d_in[10];

    float* ws   = (float*)d_ws;
    float* hq   = ws + HQ_OFF;
    float* wf   = ws + WF_OFF;
    float* sums = ws + SUMS_OFF;
    float* hard = ws + HARD_OFF;
    float* part = ws + PART_OFF;

    float* out_ct   = (float*)d_out;                 // (64,256)
    float* out_hard = (float*)d_out + BATCH * DIM;   // (2048,64)

    prep_kernel<<<BATCH + 3, 256, 0, stream>>>(
        ht_query, W_query, W_conv, W_att_past, hq, wf, sums);

    fused_kernel<<<BATCH * 32, 256, 0, stream>>>(
        ctx_key, ctx_val, ctx_mask, att_past, hq, wf, b_att_past, W_attn, b_attn,
        hard, sums, part);

    tail_kernel<<<BATCH + 128, 256, 0, stream>>>(part, hard, sums, out_ct, out_hard);
}

// Round 2
// 322.374 us; speedup vs baseline: 1.0216x; 1.0216x over previous
//
#include <hip/hip_runtime.h>
#include <math.h>

#define L_MAX 2048
#define BATCH 64
#define DIM   256
#define CCH   512
#define ROWSTRIDE (BATCH * DIM)   // floats between consecutive l at fixed b

// ws layout (floats):
#define HQ_OFF   0          // 64*256  = 16384
#define WF_OFF   16384      // 3*256   = 768
#define SUMS_OFF 17152      // 64*32 (one cache line per b) = 2048
#define HARD_OFF 19200      // 2048*64 = 131072
#define PART_OFF 150272     // 32*64*256 = 524288
#define SUMS_STRIDE 32

__device__ __forceinline__ float fast_tanh(float x) {
    float ax = fabsf(x);
    float e  = __expf(2.0f * ax);                       // inf for big ax -> r=1
    float r  = 1.0f - 2.0f * __builtin_amdgcn_rcpf(e + 1.0f);
    return copysignf(r, x);
}

// Async global->LDS, 16B per lane. LDS dest is wave-uniform base + lane*16
// (hardware adds the lane offset); global src is per-lane (must include d0).
__device__ __forceinline__ void gload16(const float* g, float* l) {
    __builtin_amdgcn_global_load_lds(
        (const __attribute__((address_space(1))) void*)g,
        (__attribute__((address_space(3))) void*)l,
        16, 0, 0);
}

// Kernel A: hq[b][d] = sum_k ht_query[b][k]*W_query[d][k]
//           wf[j][d] = sum_c W_conv[c][0][j]*W_att_past[d][c]
//           block 0 additionally zeroes sums[].
__global__ __launch_bounds__(256) void prep_kernel(
    const float* __restrict__ ht_query, const float* __restrict__ W_query,
    const float* __restrict__ W_conv,   const float* __restrict__ W_att_past,
    float* __restrict__ hq, float* __restrict__ wf, float* __restrict__ sums) {
    int t   = threadIdx.x;
    int blk = blockIdx.x;
    if (blk == 0 && t < BATCH) sums[t * SUMS_STRIDE] = 0.f;
    __shared__ float q[DIM];
    if (blk < BATCH) {
        q[t] = ht_query[blk * DIM + t];
        __syncthreads();
        const float4* wrow = (const float4*)(W_query + t * DIM);
        float acc = 0.f;
        #pragma unroll 8
        for (int k = 0; k < DIM / 4; k++) {
            float4 wv = wrow[k];
            acc += q[4*k] * wv.x + q[4*k+1] * wv.y + q[4*k+2] * wv.z + q[4*k+3] * wv.w;
        }
        hq[blk * DIM + t] = acc;
    } else {
        int j = blk - BATCH;
        const float4* wrow = (const float4*)(W_att_past + t * CCH);
        float acc = 0.f;
        #pragma unroll 8
        for (int c = 0; c < CCH / 4; c++) {
            float4 wv = wrow[c];
            acc += W_conv[(4*c  ) * 3 + j] * wv.x + W_conv[(4*c+1) * 3 + j] * wv.y
                 + W_conv[(4*c+2) * 3 + j] * wv.z + W_conv[(4*c+3) * 3 + j] * wv.w;
        }
        wf[j * DIM + t] = acc;
    }
}

// Fused kernel, v2: latency-bound fix via global_load_lds staging.
//
// Round-1 post-mortem: register bursts (v0/v1) cap bytes-in-flight at what
// the RA will hold live; at VGPR=60..100 the compiler re-batches loads with
// near-drain waits -> 17-19% HBM BW, latency-bound. sched_barrier +
// launch_bounds(256,2) only cut occupancy (37->19%) without materializing
// the burst (VGPR=100 < the 132 needed -> provably not hoisted).
//
// v2 moves the in-flight bytes into the async global_load_lds queue (zero
// VGPR cost, m97 pattern). Block = (b, 64 rows); wave w owns rows
// [16w,16w+16), processed as 4 subtiles of 4 rows:
//   compute scores(s) from kbuf  -> h (wave-uniform after butterfly)
//   conditionally DMA val rows(s) -> vbuf   (skip h==0 rows: saves bytes)
//   DMA key rows(s+1)             -> kbuf
//   __syncthreads()   // the vmcnt(0) drain; 4 blocks/CU overlap across it
//   accumulate vbuf(s)*h
// kbuf/vbuf quarters are per-wave private (same wave stages+consumes), so
// single-buffered is race-free; LDS = 16K+16K+4K -> 4 blocks/CU, 16
// waves/CU, up to ~8KB DMA in flight per wave.
__global__ __launch_bounds__(256) void fused_kernel(
    const float* __restrict__ ctx_key, const float* __restrict__ ctx_val,
    const float* __restrict__ ctx_mask, const float* __restrict__ att_past,
    const float* __restrict__ hq, const float* __restrict__ wf,
    const float* __restrict__ b_att_past, const float* __restrict__ W_attn,
    const float* __restrict__ b_attn,
    float* __restrict__ hard_raw, float* __restrict__ sums,
    float* __restrict__ part) {
    __shared__ float kbuf[16 * DIM];   // 16 rows x 1KB (4 rows per wave)
    __shared__ float vbuf[16 * DIM];
    __shared__ float red[4 * DIM];
    __shared__ float c4[4];

    int b     = blockIdx.x & 63;
    int chunk = blockIdx.x >> 6;
    int w     = threadIdx.x >> 6;
    int lane  = threadIdx.x & 63;
    int d0    = lane << 2;
    int l0w   = chunk * 64 + w * 16;   // this wave's first row

    float4 hq4 = *(const float4*)(hq + b * DIM + d0);
    float4 bp  = *(const float4*)(b_att_past + d0);
    hq4.x += bp.x; hq4.y += bp.y; hq4.z += bp.z; hq4.w += bp.w;
    float4 w0  = *(const float4*)(wf + d0);
    float4 w1  = *(const float4*)(wf + DIM + d0);
    float4 w2  = *(const float4*)(wf + 2 * DIM + d0);
    float4 wa  = *(const float4*)(W_attn + d0);
    float battn = b_attn[0];
    const float* apb = att_past + b * L_MAX;

    // att_past window [l0w-1, l0w+16]: ap[i] = apb[l0w-1+i]
    float ap[18];
    {
        float4 t0 = *(const float4*)(apb + l0w);
        float4 t1 = *(const float4*)(apb + l0w + 4);
        float4 t2 = *(const float4*)(apb + l0w + 8);
        float4 t3 = *(const float4*)(apb + l0w + 12);
        ap[1]=t0.x; ap[2]=t0.y; ap[3]=t0.z; ap[4]=t0.w;
        ap[5]=t1.x; ap[6]=t1.y; ap[7]=t1.z; ap[8]=t1.w;
        ap[9]=t2.x; ap[10]=t2.y; ap[11]=t2.z; ap[12]=t2.w;
        ap[13]=t3.x; ap[14]=t3.y; ap[15]=t3.z; ap[16]=t3.w;
        ap[0]  = (l0w > 0)          ? apb[l0w - 1]  : 0.f;
        ap[17] = (l0w + 16 < L_MAX) ? apb[l0w + 16] : 0.f;
    }

    // masks for this wave's 16 rows (uniform addr per wave -> broadcast loads)
    float m16[16];
    #pragma unroll
    for (int j = 0; j < 16; j++)
        m16[j] = ctx_mask[(l0w + j) * BATCH + b];

    // prologue: stage key subtile 0 (rows l0w..l0w+3)
    #pragma unroll
    for (int j = 0; j < 4; j++)
        gload16(ctx_key + (size_t)((l0w + j) * BATCH + b) * DIM + d0,
                &kbuf[(w * 4 + j) * DIM]);
    __syncthreads();   // drains key0 DMA

    float h16[16];
    float cnt = 0.f;
    float4 acc = make_float4(0.f, 0.f, 0.f, 0.f);

    #pragma unroll
    for (int s = 0; s < 4; s++) {
        // ---- compute scores for subtile s (rows l0w+4s..+3) ----
        float p[4];
        #pragma unroll
        for (int j = 0; j < 4; j++) {
            int r = 4 * s + j;
            float4 k = *(const float4*)&kbuf[(w * 4 + j) * DIM + d0];
            float am = ap[r], a0 = ap[r + 1], a1 = ap[r + 2];
            float x0 = k.x + hq4.x + am * w0.x + a0 * w1.x + a1 * w2.x;
            float x1 = k.y + hq4.y + am * w0.y + a0 * w1.y + a1 * w2.y;
            float x2 = k.z + hq4.z + am * w0.z + a0 * w1.z + a1 * w2.z;
            float x3 = k.w + hq4.w + am * w0.w + a0 * w1.w + a1 * w2.w;
            p[j] = fast_tanh(x0) * wa.x + fast_tanh(x1) * wa.y +
                   fast_tanh(x2) * wa.z + fast_tanh(x3) * wa.w;
        }
        #pragma unroll
        for (int off = 32; off > 0; off >>= 1) {
            #pragma unroll
            for (int j = 0; j < 4; j++)
                p[j] += __shfl_xor(p[j], off, 64);
        }
        #pragma unroll
        for (int j = 0; j < 4; j++) {
            h16[4 * s + j] = (p[j] + battn >= 0.f) ? m16[4 * s + j] : 0.f;
            cnt += h16[4 * s + j];
        }

        // ---- issue val DMAs for subtile s (h is wave-uniform: no divergence,
        //      dead rows' bytes never fetched; their vbuf slot is stale garbage
        //      but accumulate is guarded by the same uniform branch) ----
        #pragma unroll
        for (int j = 0; j < 4; j++) {
            if (h16[4 * s + j] != 0.f)
                gload16(ctx_val + (size_t)((l0w + 4 * s + j) * BATCH + b) * DIM + d0,
                        &vbuf[(w * 4 + j) * DIM]);
        }
        // ---- issue key DMAs for subtile s+1 ----
        if (s < 3) {
            #pragma unroll
            for (int j = 0; j < 4; j++)
                gload16(ctx_key + (size_t)((l0w + 4 * (s + 1) + j) * BATCH + b) * DIM + d0,
                        &kbuf[(w * 4 + j) * DIM]);
        }
        __syncthreads();   // vmcnt drain: vbuf(s) + kbuf(s+1) both landed

        // ---- accumulate vals of subtile s ----
        #pragma unroll
        for (int j = 0; j < 4; j++) {
            float hv = h16[4 * s + j];
            if (hv != 0.f) {
                float4 v = *(const float4*)&vbuf[(w * 4 + j) * DIM + d0];
                acc.x += v.x * hv; acc.y += v.y * hv;
                acc.z += v.z * hv; acc.w += v.w * hv;
            }
        }
    }

    // hard_raw writes (unnormalized), one store stream from lane 0
    if (lane == 0) {
        #pragma unroll
        for (int j = 0; j < 16; j++)
            hard_raw[(l0w + j) * BATCH + b] = h16[j];
    }

    // cross-wave reduction of acc into part
    *(float4*)(red + w * DIM + d0) = acc;
    if (lane == 0) c4[w] = cnt;
    __syncthreads();
    int d = threadIdx.x;
    float sred = red[d] + red[DIM + d] + red[2 * DIM + d] + red[3 * DIM + d];
    part[(size_t)(chunk * BATCH + b) * DIM + d] = sred;
    if (threadIdx.x == 0)
        atomicAdd(&sums[b * SUMS_STRIDE], c4[0] + c4[1] + c4[2] + c4[3]);
}

// Tail: blocks 0..63   -> ct[b][d] = (sum_chunk part) / (Z_b+1e-10)
//       blocks 64..191 -> out_hard[l][b] = hard_raw[l][b] / (Z_b+1e-10)
__global__ __launch_bounds__(256) void tail_kernel(
    const float* __restrict__ part, const float* __restrict__ hard_raw,
    const float* __restrict__ sums,
    float* __restrict__ ct, float* __restrict__ out_hard) {
    if (blockIdx.x < BATCH) {
        int b = blockIdx.x;
        int d = threadIdx.x;
        float s = 0.f;
        #pragma unroll 8
        for (int c = 0; c < 32; c++)
            s += part[(size_t)(c * BATCH + b) * DIM + d];
        float invZ = 1.0f / (sums[b * SUMS_STRIDE] + 1e-10f);
        ct[b * DIM + d] = s * invZ;
    } else {
        int i = (blockIdx.x - BATCH) * 256 + threadIdx.x;   // 4 elems each
        float4 h = *(const float4*)(hard_raw + (size_t)i * 4);
        int b0 = (i * 4) & 63;
        float4 o;
        o.x = h.x / (sums[(b0 + 0) * SUMS_STRIDE] + 1e-10f);
        o.y = h.y / (sums[(b0 + 1) * SUMS_STRIDE] + 1e-10f);
        o.z = h.z / (sums[(b0 + 2) * SUMS_STRIDE] + 1e-10f);
        o.w = h.w / (sums[(b0 + 3) * SUMS_STRIDE] + 1e-10f);
        *(float4*)(out_hard + (size_t)i * 4) = o;
    }
}

extern "C" void kernel_launch(void* const* d_in, const int* in_sizes, int n_in,
                              void* d_out, int out_size, void* d_ws, size_t ws_size,
                              hipStream_t stream) {
    const float* ctx_val    = (const float*)d_in[0];
    const float* ctx_key    = (const float*)d_in[1];
    const float* ctx_mask   = (const float*)d_in[2];
    const float* att_past   = (const float*)d_in[3];
    const float* ht_query   = (const float*)d_in[4];
    const float* W_conv     = (const float*)d_in[5];
    const float* W_query    = (const float*)d_in[6];
    const float* W_att_past = (const float*)d_in[7];
    const float* b_att_past = (const float*)d_in[8];
    const float* W_attn     = (const float*)d_in[9];
    const float* b_attn     = (const float*)d_in[10];

    float* ws   = (float*)d_ws;
    float* hq   = ws + HQ_OFF;
    float* wf   = ws + WF_OFF;
    float* sums = ws + SUMS_OFF;
    float* hard = ws + HARD_OFF;
    float* part = ws + PART_OFF;

    float* out_ct   = (float*)d_out;                 // (64,256)
    float* out_hard = (float*)d_out + BATCH * DIM;   // (2048,64)

    prep_kernel<<<BATCH + 3, 256, 0, stream>>>(
        ht_query, W_query, W_conv, W_att_past, hq, wf, sums);

    fused_kernel<<<BATCH * 32, 256, 0, stream>>>(
        ctx_key, ctx_val, ctx_mask, att_past, hq, wf, b_att_past, W_attn, b_attn,
        hard, sums, part);

    tail_kernel<<<BATCH + 128, 256, 0, stream>>>(part, hard, sums, out_ct, out_hard);
}